// Round 11
// baseline (241.981 us; speedup 1.0000x reference)
//
#include <hip/hip_runtime.h>
#include <hip/hip_bf16.h>
#include <stdint.h>

// Problem constants (FlaxGPTNeoSelfAttention): B=2, S=2048, D=2048, H=16, HD=128
#define Bv 2
#define Sv 2048
#define Dv 2048
#define Hv 16
#define HDv 128
#define Mv (Bv*Sv)   // 4096 rows for the projection GEMMs

typedef __attribute__((ext_vector_type(8))) short short8;
typedef __attribute__((ext_vector_type(4))) short short4v;
typedef __attribute__((ext_vector_type(4))) float f32x4;

union PU { uint32_t u[4]; short8 s; };

__device__ __forceinline__ unsigned short bf16_rne(float f) {
    union { float f; uint32_t u; } c; c.f = f;
    uint32_t u = c.u;
    u += 0x7fffu + ((u >> 16) & 1u);   // round-to-nearest-even
    return (unsigned short)(u >> 16);
}

__device__ __forceinline__ uint32_t cvt_pk_bf16(float lo, float hi) {
    uint32_t r;
    asm("v_cvt_pk_bf16_f32 %0, %1, %2" : "=v"(r) : "v"(lo), "v"(hi));
    return r;
}

__device__ __forceinline__ void gload16(const void* g, void* l) {
    // async global->LDS, 16B per lane; LDS dest = wave-uniform base + lane*16
    __builtin_amdgcn_global_load_lds((const __attribute__((address_space(1))) void*)g,
                                     (__attribute__((address_space(3))) void*)l, 16, 0, 0);
}

#define BARRIER() asm volatile("s_barrier" ::: "memory")
#define LGKM0()   do { asm volatile("s_waitcnt lgkmcnt(0)" ::: "memory"); \
                       __builtin_amdgcn_sched_barrier(0); } while (0)

// ---------------- kernel 1: hidden_states fp32 -> bf16 ----------------
__global__ void cvt_x_kernel(const float* __restrict__ x, unsigned short* __restrict__ xb) {
    int i = (blockIdx.x * 256 + threadIdx.x) * 4;
    float4 v = *(const float4*)(x + i);
    short4v o;
    o[0] = (short)bf16_rne(v.x);
    o[1] = (short)bf16_rne(v.y);
    o[2] = (short)bf16_rne(v.z);
    o[3] = (short)bf16_rne(v.w);
    *(short4v*)(xb + i) = o;
}

// ---------------- kernel 2: weights fp32 -> bf16, transposed Wt[n][k] ----------------
__global__ void cvt_wt_kernel(const float* __restrict__ w0, const float* __restrict__ w1,
                              const float* __restrict__ w2, const float* __restrict__ w3,
                              unsigned short* __restrict__ wt) {
    __shared__ unsigned short t[64][65];
    int z = blockIdx.z;
    const float* w = (z == 0) ? w0 : (z == 1) ? w1 : (z == 2) ? w2 : w3;
    unsigned short* o = wt + (size_t)z * Dv * Dv;
    int k0 = blockIdx.x * 64, n0 = blockIdx.y * 64;
    for (int i = threadIdx.x; i < 4096; i += 256) {
        int r = i >> 6, c = i & 63;
        t[r][c] = bf16_rne(w[(size_t)(k0 + r) * Dv + n0 + c]);
    }
    __syncthreads();
    for (int i = threadIdx.x; i < 4096; i += 256) {
        int r = i >> 6, c = i & 63;
        o[(size_t)(n0 + r) * Dv + k0 + c] = t[c][r];
    }
}

// ---------------- kernel 2b: V (bf16 [4096][2048]) -> VT per batch ([b*2048+c][s]) ----------------
__global__ void vt_kernel(const unsigned short* __restrict__ V, unsigned short* __restrict__ VT) {
    __shared__ unsigned short t[64 * 64];   // XOR chunk-swizzled 64x64 tile
    const int tid = threadIdx.x;
    const int b = blockIdx.z;
    const int s0 = blockIdx.x * 64, c0 = blockIdx.y * 64;
    const unsigned short* Vb = V + (size_t)b * Sv * Dv;
    unsigned short* VTb = VT + (size_t)b * Dv * Sv;
    #pragma unroll
    for (int ii = 0; ii < 2; ++ii) {
        int i = tid + ii * 256;
        int r = i >> 3, ch = i & 7;
        short8 v = *(const short8*)&Vb[(size_t)(s0 + r) * Dv + c0 + ch * 8];
        *(short8*)&t[r * 64 + ((ch ^ (r & 7)) << 3)] = v;
    }
    __syncthreads();
    #pragma unroll
    for (int ii = 0; ii < 2; ++ii) {
        int o = tid + ii * 256;
        int orow = o >> 3, och = o & 7;
        short8 v;
        #pragma unroll
        for (int j = 0; j < 8; ++j) {
            int r = och * 8 + j;
            int c = orow;
            v[j] = (short)t[r * 64 + ((((c >> 3) ^ (r & 7)) << 3) | (c & 7))];
        }
        *(short8*)&VTb[(size_t)(c0 + orow) * Sv + s0 + och * 8] = v;
    }
}

// ---------------- kernel 3a: QK projection, 8-phase 256x256 ----------------
__global__ __launch_bounds__(512, 2) void gemm8ph_kernel(
    const unsigned short* __restrict__ A,
    const unsigned short* __restrict__ WtBase,
    unsigned short* __restrict__ CbBase)
{
    extern __shared__ unsigned short lds[];   // 65536 shorts = 128 KiB
    const int tid = threadIdx.x;
    const int wv = tid >> 6, ln = tid & 63;
    const int lr = ln & 15, lg = ln >> 4;
    const int wm = wv >> 2, wn = wv & 3;      // 2 x 4 waves

    const int bid = blockIdx.x;
    const int xcd = bid & 7, idx = bid >> 3;
    const int n_idx = xcd * 2 + idx / 16;     // 0..15
    const int m_idx = idx % 16;
    const int m0 = m_idx * 256, n0g = n_idx * 256;

    const int lrow = wv * 8 + (ln >> 3);
    const int lcol = ((ln & 7) ^ (ln >> 3)) << 3;
    const unsigned short* Ag = A      + (size_t)(m0  + lrow) * Dv + lcol;
    const unsigned short* Bg = WtBase + (size_t)(n0g + lrow) * Dv + lcol;

    auto SH = [&](int T, int isB, int h) {
        const unsigned short* src = (isB ? Bg : Ag) + (size_t)(h * 128) * Dv + T * 64;
        unsigned short* dst = &lds[(T & 1) * 32768 + isB * 16384 + h * 8192 + wv * 512];
        gload16(src, dst);
        gload16(src + (size_t)64 * Dv, dst + 4096);
    };

    const int axk = lr & 7;
    auto RDA = [&](int buf, int fm, int ks) {
        return *(const short8*)&lds[buf * 32768 + (wm * 128 + fm * 16 + lr) * 64 + (((ks * 4 + lg) ^ axk) << 3)];
    };
    auto RDB = [&](int buf, int fn, int ks) {
        return *(const short8*)&lds[buf * 32768 + 16384 + (wn * 64 + fn * 16 + lr) * 64 + (((ks * 4 + lg) ^ axk) << 3)];
    };

    f32x4 acc[8][4];
    #pragma unroll
    for (int fm = 0; fm < 8; fm++)
        #pragma unroll
        for (int fn = 0; fn < 4; fn++)
            acc[fm][fn] = (f32x4){0.f, 0.f, 0.f, 0.f};

    SH(0, 0, 0); SH(0, 0, 1); SH(0, 1, 0); SH(0, 1, 1);
    SH(1, 1, 0); SH(1, 0, 0);
    asm volatile("s_waitcnt vmcnt(4)" ::: "memory");
    BARRIER();

    short8 af[8], b0[4], b1[4];
    const int NT2 = 16;

    #define MFMA_BLK(FN0, FN1, BARR) do {                                              \
        __builtin_amdgcn_s_setprio(1);                                                 \
        _Pragma("unroll")                                                              \
        for (int fm = 0; fm < 8; fm++) {                                               \
            acc[fm][FN0] = __builtin_amdgcn_mfma_f32_16x16x32_bf16(af[fm], BARR[FN0], acc[fm][FN0], 0, 0, 0); \
            acc[fm][FN1] = __builtin_amdgcn_mfma_f32_16x16x32_bf16(af[fm], BARR[FN1], acc[fm][FN1], 0, 0, 0); \
        }                                                                              \
        __builtin_amdgcn_s_setprio(0);                                                 \
    } while (0)

    for (int i = 0; i < NT2; ++i) {
        const int Tb = 2 * i + 1;
        const bool more = (i + 1 < NT2);

        #pragma unroll
        for (int fm = 0; fm < 8; fm++) af[fm] = RDA(0, fm, 0);
        #pragma unroll
        for (int fn = 0; fn < 4; fn++) b0[fn] = RDB(0, fn, 0);
        SH(Tb, 0, 1);
        BARRIER(); LGKM0();
        MFMA_BLK(0, 1, b0);
        BARRIER();

        #pragma unroll
        for (int fn = 0; fn < 4; fn++) b1[fn] = RDB(0, fn, 1);
        SH(Tb, 1, 1);
        BARRIER(); LGKM0();
        MFMA_BLK(2, 3, b0);
        BARRIER();

        #pragma unroll
        for (int fm = 0; fm < 8; fm++) af[fm] = RDA(0, fm, 1);
        if (more) SH(Tb + 1, 1, 0);
        BARRIER(); LGKM0();
        MFMA_BLK(0, 1, b1);
        BARRIER();

        if (more) SH(Tb + 1, 0, 0);
        BARRIER(); LGKM0();
        MFMA_BLK(2, 3, b1);
        if (more) asm volatile("s_waitcnt vmcnt(4)" ::: "memory");
        else      asm volatile("s_waitcnt vmcnt(0)" ::: "memory");
        BARRIER();

        #pragma unroll
        for (int fm = 0; fm < 8; fm++) af[fm] = RDA(1, fm, 0);
        #pragma unroll
        for (int fn = 0; fn < 4; fn++) b0[fn] = RDB(1, fn, 0);
        if (more) SH(Tb + 1, 0, 1);
        BARRIER(); LGKM0();
        MFMA_BLK(0, 1, b0);
        BARRIER();

        #pragma unroll
        for (int fn = 0; fn < 4; fn++) b1[fn] = RDB(1, fn, 1);
        if (more) SH(Tb + 1, 1, 1);
        BARRIER(); LGKM0();
        MFMA_BLK(2, 3, b0);
        BARRIER();

        #pragma unroll
        for (int fm = 0; fm < 8; fm++) af[fm] = RDA(1, fm, 1);
        if (more) SH(Tb + 2, 1, 0);
        BARRIER(); LGKM0();
        MFMA_BLK(0, 1, b1);
        BARRIER();

        if (more) SH(Tb + 2, 0, 0);
        BARRIER(); LGKM0();
        MFMA_BLK(2, 3, b1);
        if (more) {
            asm volatile("s_waitcnt vmcnt(4)" ::: "memory");
            BARRIER();
        }
    }
    #undef MFMA_BLK

    const int z = n0g >> 11;
    unsigned short* Cz = CbBase + (size_t)z * Mv * Dv;
    const int ncl = (n0g & 2047) + wn * 64;
    #pragma unroll
    for (int fm = 0; fm < 8; fm++)
        #pragma unroll
        for (int fn = 0; fn < 4; fn++) {
            int row = m0 + wm * 128 + fm * 16 + lg * 4;
            int col = ncl + fn * 16 + lr;
            #pragma unroll
            for (int r = 0; r < 4; r++)
                Cz[(size_t)(row + r) * Dv + col] = bf16_rne(acc[fm][fn][r]);
        }
}

// ---------------- kernel 3b/5: ring GEMM, 128x256 tile, N=2048, 256 blocks ----------------
template<int FOUT>
__global__ __launch_bounds__(512, 2) void gemm8_kernel(
    const unsigned short* __restrict__ A,
    const unsigned short* __restrict__ WtBase,
    unsigned short* __restrict__ Cb,
    float* __restrict__ Cf,
    const float* __restrict__ bias)
{
    extern __shared__ unsigned short lds[];
    const int tid = threadIdx.x;
    const int wv = tid >> 6, ln = tid & 63;
    const int lr = ln & 15, lg = ln >> 4;
    const int wm = wv >> 2, wn = wv & 3;

    const int bid = blockIdx.x;
    const int xcd = bid & 7, idx = bid >> 3;
    const int n_idx = xcd;
    const int m_idx = idx;
    const int m0 = m_idx * 128;
    const int n0g = n_idx * 256;
    const int NT = Dv / 64;

    const int srow = ln >> 3;
    const int swz = ((ln & 7) ^ srow) << 3;
    const unsigned short* Ab = A      + (size_t)(m0  + wv * 8 + srow) * Dv + swz;
    const unsigned short* Bb = WtBase + (size_t)(n0g + wv * 8 + srow) * Dv + swz;

    auto STAGE_A = [&](int t, int d) {
        const unsigned short* g = Ab + t * 64;
        #pragma unroll
        for (int j = 0; j < 2; ++j)
            gload16(g + (size_t)(j * 64) * Dv, &lds[d * 24576 + (j * 64 + wv * 8) * 64]);
    };
    auto STAGE_B = [&](int t, int d) {
        const unsigned short* g = Bb + t * 64;
        #pragma unroll
        for (int j = 0; j < 4; ++j)
            gload16(g + (size_t)(j * 64) * Dv, &lds[d * 24576 + 8192 + (j * 64 + wv * 8) * 64]);
    };

    const int aro = (wm * 64 + lr) * 64;
    const int bro = (wn * 64 + lr) * 64;
    const int ach0 = ((lg ^ (lr & 7)) << 3);
    const int ach1 = (((4 + lg) ^ (lr & 7)) << 3);

    f32x4 acc[4][4];
    #pragma unroll
    for (int mi = 0; mi < 4; mi++)
        #pragma unroll
        for (int ni = 0; ni < 4; ni++)
            acc[mi][ni] = (f32x4){0.f, 0.f, 0.f, 0.f};

    STAGE_A(0, 0); STAGE_B(0, 0);
    STAGE_A(1, 1); STAGE_B(1, 1);
    asm volatile("s_waitcnt vmcnt(6)" ::: "memory");
    BARRIER();

    for (int t = 0; t < NT; ++t) {
        const int d = t % 3, d2 = (t + 2) % 3;
        const unsigned short* la = &lds[d * 24576];
        const unsigned short* lb = &lds[d * 24576 + 8192];

        short8 af[4][2], bf0[2][2];
        #pragma unroll
        for (int mi = 0; mi < 4; mi++) {
            af[mi][0] = *(const short8*)&la[aro + mi * 1024 + ach0];
            af[mi][1] = *(const short8*)&la[aro + mi * 1024 + ach1];
        }
        #pragma unroll
        for (int ni = 0; ni < 2; ni++) {
            bf0[ni][0] = *(const short8*)&lb[bro + ni * 1024 + ach0];
            bf0[ni][1] = *(const short8*)&lb[bro + ni * 1024 + ach1];
        }
        if (t + 2 < NT) STAGE_A(t + 2, d2);
        BARRIER();
        __builtin_amdgcn_s_setprio(1);
        #pragma unroll
        for (int mi = 0; mi < 4; mi++)
            #pragma unroll
            for (int ni = 0; ni < 2; ni++) {
                acc[mi][ni] = __builtin_amdgcn_mfma_f32_16x16x32_bf16(af[mi][0], bf0[ni][0], acc[mi][ni], 0, 0, 0);
                acc[mi][ni] = __builtin_amdgcn_mfma_f32_16x16x32_bf16(af[mi][1], bf0[ni][1], acc[mi][ni], 0, 0, 0);
            }
        __builtin_amdgcn_s_setprio(0);

        short8 bf1[2][2];
        #pragma unroll
        for (int ni = 0; ni < 2; ni++) {
            bf1[ni][0] = *(const short8*)&lb[bro + (ni + 2) * 1024 + ach0];
            bf1[ni][1] = *(const short8*)&lb[bro + (ni + 2) * 1024 + ach1];
        }
        if (t + 2 < NT) STAGE_B(t + 2, d2);
        asm volatile("s_waitcnt vmcnt(6)" ::: "memory");
        BARRIER();
        __builtin_amdgcn_s_setprio(1);
        #pragma unroll
        for (int mi = 0; mi < 4; mi++)
            #pragma unroll
            for (int ni = 0; ni < 2; ni++) {
                acc[mi][ni + 2] = __builtin_amdgcn_mfma_f32_16x16x32_bf16(af[mi][0], bf1[ni][0], acc[mi][ni + 2], 0, 0, 0);
                acc[mi][ni + 2] = __builtin_amdgcn_mfma_f32_16x16x32_bf16(af[mi][1], bf1[ni][1], acc[mi][ni + 2], 0, 0, 0);
            }
        __builtin_amdgcn_s_setprio(0);
    }

    #pragma unroll
    for (int mi = 0; mi < 4; mi++)
        #pragma unroll
        for (int ni = 0; ni < 4; ni++) {
            int row = m0 + wm * 64 + mi * 16 + lg * 4;
            int col = n0g + wn * 64 + ni * 16 + lr;
            if (FOUT) {
                float bv = bias[col];
                #pragma unroll
                for (int r = 0; r < 4; r++)
                    Cf[(size_t)(row + r) * Dv + col] = acc[mi][ni][r] + bv;
            } else {
                #pragma unroll
                for (int r = 0; r < 4; r++)
                    Cb[(size_t)(row + r) * Dv + col] = bf16_rne(acc[mi][ni][r]);
            }
        }
}

// ---------------- kernel 4: causal flash attention, dual-q-group (pair p, 15-p) ----------------
// 256 blocks (32 bh x 8 pairs), 8 waves; each wave: 16 q-rows of tile p (L) +
// 16 q-rows of tile 15-p (H). K/V^T LDS fragments read ONCE, fed to both groups.
__global__ __launch_bounds__(512) void attn_kernel(
    const unsigned short* __restrict__ Q, const unsigned short* __restrict__ K,
    const unsigned short* __restrict__ VT, const int* __restrict__ pmask,
    unsigned short* __restrict__ CTX)
{
    __shared__ unsigned short lK[2][64 * 128];
    __shared__ unsigned short lVt[2][128 * 64];
    __shared__ int lPmB[2][64];
    __shared__ int lPmOk[2];

    const int tid = threadIdx.x, wv = tid >> 6, ln = tid & 63;
    const int lr = ln & 15, lg = ln >> 4;
    const int L = blockIdx.x;                      // 256 blocks
    const int bh = (L & 7) * 4 + ((L >> 3) & 3);   // 4 bh per XCD
    const int b = bh >> 4, h = bh & 15;
    const int p = L >> 5;                          // 0..7 pair index
    const int q0l = p * 128, q0h = (15 - p) * 128;
    const int qw0l = q0l + wv * 16, qw0h = q0h + wv * 16;
    const size_t hoff  = (size_t)b * Sv * Dv + (size_t)h * HDv;
    const size_t vtoff = ((size_t)b * Dv + (size_t)h * HDv) * Sv;

    short8 qfL[4], qfH[4];
    #pragma unroll
    for (int ds = 0; ds < 4; ds++) {
        qfL[ds] = *(const short8*)&Q[hoff + (size_t)(qw0l + lr) * Dv + ds * 32 + lg * 8];
        qfH[ds] = *(const short8*)&Q[hoff + (size_t)(qw0h + lr) * Dv + ds * 32 + lg * 8];
    }

    size_t koff[2], voff[2];
    #pragma unroll
    for (int ii = 0; ii < 2; ++ii) {
        int slot = ii * 512 + wv * 64 + ln;
        int krow = slot >> 4, kch = slot & 15;
        koff[ii] = hoff + (size_t)krow * Dv + ((kch ^ (krow & 7)) << 3);
        int vrow = slot >> 3, vch = slot & 7;
        voff[ii] = vtoff + (size_t)vrow * Sv + ((vch ^ (vrow & 7)) << 3);
    }

    auto STAGE = [&](int t, int buf) {
        const size_t kadd = (size_t)(t << 6) * Dv;
        const int vadd = t << 6;
        unsigned short* kb = &lK[buf][0];
        unsigned short* vb = &lVt[buf][0];
        #pragma unroll
        for (int ii = 0; ii < 2; ++ii) {
            gload16(K + koff[ii] + kadd, kb + (ii * 512 + wv * 64) * 8);
            gload16(VT + voff[ii] + vadd, vb + (ii * 512 + wv * 64) * 8);
        }
        if (wv == 0) {
            int pmv = pmask[b * Sv + (t << 6) + ln];
            lPmB[buf][ln] = pmv;
            unsigned long long bal = __ballot(pmv != 0);
            if (ln == 0) lPmOk[buf] = (bal == ~0ull) ? 1 : 0;
        }
    };

    f32x4 accL[8], accH[8];
    #pragma unroll
    for (int n = 0; n < 8; n++) {
        accL[n] = (f32x4){0.f, 0.f, 0.f, 0.f};
        accH[n] = (f32x4){0.f, 0.f, 0.f, 0.f};
    }
    float mrowL = -3.0e38f, lrowL = 0.f;
    float mrowH = -3.0e38f, lrowH = 0.f;
    const float CS = 0.12751744f;               // (1/sqrt(128)) * log2(e)
    const int qgL = qw0l + lr, qgH = qw0h + lr;
    const int nt = (q0h >> 6) + 2;
    const int srcA = lr + ((lg & 1) << 5);
    const int srcB = srcA + 16;
    const bool hiSel = (lg >= 2);

    // per-group softmax + pack + exchange; st in, pa0/pa1 out
    auto GROUP_SM = [&](const f32x4 (&st)[4], f32x4 (&acc)[8], float& mrow, float& lrow,
                        int qg, int kv0, int buf, PU& pa0, PU& pa1, auto DIAG_c) {
        constexpr bool DIAG = decltype(DIAG_c)::value;
        float sv[4][4];
        float rmax;
        if constexpr (DIAG) {
            const int* pm = &lPmB[buf][0];
            #pragma unroll
            for (int t2 = 0; t2 < 4; ++t2)
                #pragma unroll
                for (int r = 0; r < 4; ++r) {
                    int kvl = t2 * 16 + lg * 4 + r;
                    bool ok = ((kv0 + kvl) <= qg) && (pm[kvl] != 0);
                    sv[t2][r] = ok ? st[t2][r] * CS : -1.0e30f;
                }
            rmax = sv[0][0];
            #pragma unroll
            for (int t2 = 0; t2 < 4; ++t2)
                #pragma unroll
                for (int r = 0; r < 4; ++r) rmax = fmaxf(rmax, sv[t2][r]);
            rmax = fmaxf(rmax, __shfl_xor(rmax, 16, 64));
            rmax = fmaxf(rmax, __shfl_xor(rmax, 32, 64));
        } else {
            rmax = st[0][0];
            #pragma unroll
            for (int t2 = 0; t2 < 4; ++t2)
                #pragma unroll
                for (int r = 0; r < 4; ++r) rmax = fmaxf(rmax, st[t2][r]);
            rmax = fmaxf(rmax, __shfl_xor(rmax, 16, 64));
            rmax = fmaxf(rmax, __shfl_xor(rmax, 32, 64));
            rmax *= CS;
        }

        if (!__all(rmax - mrow <= 8.0f)) {     // T13 defer-max
            float mn = fmaxf(mrow, rmax);
            float alpha = exp2f(mrow - mn);
            mrow = mn;
            lrow *= alpha;
            #pragma unroll
            for (int n = 0; n < 8; n++)
                #pragma unroll
                for (int r = 0; r < 4; r++) acc[n][r] *= alpha;
        }

        float pr[4][4]; float psum = 0.f;
        if constexpr (DIAG) {
            #pragma unroll
            for (int t2 = 0; t2 < 4; ++t2)
                #pragma unroll
                for (int r = 0; r < 4; ++r) {
                    float e = exp2f(sv[t2][r] - mrow);
                    pr[t2][r] = (sv[t2][r] > -5.0e29f) ? e : 0.f;
                    psum += pr[t2][r];
                }
        } else {
            if (lPmOk[buf]) {
                #pragma unroll
                for (int t2 = 0; t2 < 4; ++t2)
                    #pragma unroll
                    for (int r = 0; r < 4; ++r) {
                        pr[t2][r] = exp2f(fmaf(st[t2][r], CS, -mrow));
                        psum += pr[t2][r];
                    }
            } else {
                const int* pm = &lPmB[buf][0];
                #pragma unroll
                for (int t2 = 0; t2 < 4; ++t2)
                    #pragma unroll
                    for (int r = 0; r < 4; ++r) {
                        int kvl = t2 * 16 + lg * 4 + r;
                        float e = exp2f(fmaf(st[t2][r], CS, -mrow));
                        pr[t2][r] = (pm[kvl] != 0) ? e : 0.f;
                        psum += pr[t2][r];
                    }
            }
        }
        psum += __shfl_xor(psum, 16, 64);
        psum += __shfl_xor(psum, 32, 64);
        lrow += psum;

        uint32_t pk[4][2];
        #pragma unroll
        for (int t2 = 0; t2 < 4; ++t2)
            #pragma unroll
            for (int pp = 0; pp < 2; ++pp)
                pk[t2][pp] = cvt_pk_bf16(pr[t2][2 * pp], pr[t2][2 * pp + 1]);

        {
            uint32_t l0 = (uint32_t)__shfl((int)pk[0][0], srcA, 64), h0 = (uint32_t)__shfl((int)pk[1][0], srcA, 64);
            uint32_t l1 = (uint32_t)__shfl((int)pk[0][1], srcA, 64), h1 = (uint32_t)__shfl((int)pk[1][1], srcA, 64);
            uint32_t l2 = (uint32_t)__shfl((int)pk[0][0], srcB, 64), h2 = (uint32_t)__shfl((int)pk[1][0], srcB, 64);
            uint32_t l3 = (uint32_t)__shfl((int)pk[0][1], srcB, 64), h3 = (uint32_t)__shfl((int)pk[1][1], srcB, 64);
            pa0.u[0] = hiSel ? h0 : l0; pa0.u[1] = hiSel ? h1 : l1;
            pa0.u[2] = hiSel ? h2 : l2; pa0.u[3] = hiSel ? h3 : l3;
        }
        {
            uint32_t l0 = (uint32_t)__shfl((int)pk[2][0], srcA, 64), h0 = (uint32_t)__shfl((int)pk[3][0], srcA, 64);
            uint32_t l1 = (uint32_t)__shfl((int)pk[2][1], srcA, 64), h1 = (uint32_t)__shfl((int)pk[3][1], srcA, 64);
            uint32_t l2 = (uint32_t)__shfl((int)pk[2][0], srcB, 64), h2 = (uint32_t)__shfl((int)pk[3][0], srcB, 64);
            uint32_t l3 = (uint32_t)__shfl((int)pk[2][1], srcB, 64), h3 = (uint32_t)__shfl((int)pk[3][1], srcB, 64);
            pa1.u[0] = hiSel ? h0 : l0; pa1.u[1] = hiSel ? h1 : l1;
            pa1.u[2] = hiSel ? h2 : l2; pa1.u[3] = hiSel ? h3 : l3;
        }
    };

    // dual tile: K/VT frags read once, both groups' MFMAs fed
    auto TILE = [&](int t, int buf, auto DOL_c, auto DIAG_c) {
        constexpr bool DOL = decltype(DOL_c)::value;
        const int kv0 = t << 6;
        const unsigned short* kb = &lK[buf][0];
        const unsigned short* vb = &lVt[buf][0];

        f32x4 stL[4], stH[4];
        #pragma unroll
        for (int t2 = 0; t2 < 4; ++t2) {
            stH[t2] = (f32x4){0.f, 0.f, 0.f, 0.f};
            if constexpr (DOL) stL[t2] = (f32x4){0.f, 0.f, 0.f, 0.f};
        }
        __builtin_amdgcn_s_setprio(1);
        #pragma unroll
        for (int t2 = 0; t2 < 4; ++t2) {
            const int krow = t2 * 16 + lr;
            #pragma unroll
            for (int ds = 0; ds < 4; ++ds) {
                const int ch = ds * 4 + lg;
                short8 kf = *(const short8*)&kb[krow * 128 + ((ch ^ (krow & 7)) << 3)];
                stH[t2] = __builtin_amdgcn_mfma_f32_16x16x32_bf16(kf, qfH[ds], stH[t2], 0, 0, 0);
                if constexpr (DOL)
                    stL[t2] = __builtin_amdgcn_mfma_f32_16x16x32_bf16(kf, qfL[ds], stL[t2], 0, 0, 0);
            }
        }
        __builtin_amdgcn_s_setprio(0);

        PU paH0, paH1, paL0, paL1;
        GROUP_SM(stH, accH, mrowH, lrowH, qgH, kv0, buf, paH0, paH1, DIAG_c);
        if constexpr (DOL)
            GROUP_SM(stL, accL, mrowL, lrowL, qgL, kv0, buf, paL0, paL1, DIAG_c);

        __builtin_amdgcn_s_setprio(1);
        #pragma unroll
        for (int n = 0; n < 8; n++) {
            const int vrow = n * 16 + lr;
            short8 a0 = *(const short8*)&vb[vrow * 64 + ((lg ^ (vrow & 7)) << 3)];
            short8 a1 = *(const short8*)&vb[vrow * 64 + (((4 + lg) ^ (vrow & 7)) << 3)];
            accH[n] = __builtin_amdgcn_mfma_f32_16x16x32_bf16(a0, paH0.s, accH[n], 0, 0, 0);
            accH[n] = __builtin_amdgcn_mfma_f32_16x16x32_bf16(a1, paH1.s, accH[n], 0, 0, 0);
            if constexpr (DOL) {
                accL[n] = __builtin_amdgcn_mfma_f32_16x16x32_bf16(a0, paL0.s, accL[n], 0, 0, 0);
                accL[n] = __builtin_amdgcn_mfma_f32_16x16x32_bf16(a1, paL1.s, accL[n], 0, 0, 0);
            }
        }
        __builtin_amdgcn_s_setprio(0);
    };

    STAGE(0, 0);
    __syncthreads();
    int cur = 0;

    using TrueC  = std::integral_constant<bool, true>;
    using FalseC = std::integral_constant<bool, false>;

    for (int t = 0; t < nt; ++t) {
        if (t + 1 < nt) STAGE(t + 1, cur ^ 1);
        const int kv0 = t << 6;
        if (kv0 <= qw0h + 15) {                    // H active (L active implies H active)
            const bool doL = (kv0 <= qw0l + 15);
            const bool diag = (kv0 + 63 > qw0h) || (doL && (kv0 + 63 > qw0l));
            if (doL) {
                if (diag) TILE(t, cur, TrueC{}, TrueC{});
                else      TILE(t, cur, TrueC{}, FalseC{});
            } else {
                if (diag) TILE(t, cur, FalseC{}, TrueC{});
                else      TILE(t, cur, FalseC{}, FalseC{});
            }
        }
        __syncthreads();
        cur ^= 1;
    }

    // epilogue: both groups
    float invL = 1.0f / lrowL, invH = 1.0f / lrowH;
    #pragma unroll
    for (int n = 0; n < 8; n++) {
        short4v oL, oH;
        #pragma unroll
        for (int r = 0; r < 4; r++) {
            oL[r] = (short)bf16_rne(accL[n][r] * invL);
            oH[r] = (short)bf16_rne(accH[n][r] * invH);
        }
        *(short4v*)&CTX[hoff + (size_t)qgL * Dv + n * 16 + lg * 4] = oL;
        *(short4v*)&CTX[hoff + (size_t)qgH * Dv + n * 16 + lg * 4] = oH;
    }
}

// ---------------- launcher ----------------
extern "C" void kernel_launch(void* const* d_in, const int* in_sizes, int n_in,
                              void* d_out, int out_size, void* d_ws, size_t ws_size,
                              hipStream_t stream) {
    const float* hs  = (const float*)d_in[0];
    const int*   am  = (const int*)d_in[1];
    const float* wq  = (const float*)d_in[2];
    const float* wk  = (const float*)d_in[3];
    const float* wv_ = (const float*)d_in[4];
    const float* wo  = (const float*)d_in[5];
    const float* bo  = (const float*)d_in[6];
    float* out = (float*)d_out;

    char* ws = (char*)d_ws;
    unsigned short* Xb  = (unsigned short*)ws;                               // 16 MiB: X bf16; later VT
    unsigned short* Wt  = (unsigned short*)(ws + (size_t)16 * 1024 * 1024);  // 32 MiB: 4x Wt bf16
    unsigned short* QKV = (unsigned short*)(ws + (size_t)48 * 1024 * 1024);  // 48 MiB: Q,K,V bf16
    unsigned short* CTX = (unsigned short*)(ws + (size_t)96 * 1024 * 1024);  // 16 MiB: ctx bf16
    unsigned short* VT  = Xb;                                                // alias (Xb dead after projections)

    const int LDSB_8PH = 131072;      // 128 KiB dynamic LDS
    const int LDSB_R   = 147456;      // 144 KiB dynamic LDS
    static bool attrSet = false;
    if (!attrSet) {
        hipFuncSetAttribute((const void*)gemm8ph_kernel, hipFuncAttributeMaxDynamicSharedMemorySize, LDSB_8PH);
        hipFuncSetAttribute((const void*)gemm8_kernel<0>, hipFuncAttributeMaxDynamicSharedMemorySize, LDSB_R);
        hipFuncSetAttribute((const void*)gemm8_kernel<1>, hipFuncAttributeMaxDynamicSharedMemorySize, LDSB_R);
        attrSet = true;
    }

    hipLaunchKernelGGL(cvt_x_kernel, dim3(Mv * Dv / 4 / 256), dim3(256), 0, stream, hs, Xb);
    hipLaunchKernelGGL(cvt_wt_kernel, dim3(32, 32, 4), dim3(256), 0, stream, wq, wk, wv_, wo, Wt);
    // QK projection: 8-phase 256^2, N=4096 (wq,wk), 256 blocks = 1 exact CU round
    hipLaunchKernelGGL(gemm8ph_kernel, dim3(256), dim3(512), LDSB_8PH, stream, Xb, Wt, QKV);
    // V projection: ring gemm, N=2048 (wv), 256 blocks = 1 exact CU round, bf16 out
    hipLaunchKernelGGL(gemm8_kernel<0>, dim3(256), dim3(512), LDSB_R, stream,
                       Xb, Wt + 2 * (size_t)Dv * Dv, QKV + 2 * (size_t)Mv * Dv, (float*)nullptr, (const float*)nullptr);
    hipLaunchKernelGGL(vt_kernel, dim3(32, 32, 2), dim3(256), 0, stream,
                       QKV + 2 * (size_t)Mv * Dv, VT);
    // attention: dual-q-group pairs, 256 blocks (32 bh x 8 pairs)
    hipLaunchKernelGGL(attn_kernel, dim3(256), dim3(512), 0, stream,
                       QKV, QKV + (size_t)Mv * Dv, VT, am, CTX);
    // out-proj: N=2048, 256 blocks = 1 exact CU round, fp32 + bias
    hipLaunchKernelGGL(gemm8_kernel<1>, dim3(256), dim3(512), LDSB_R, stream,
                       CTX, Wt + 3 * (size_t)Dv * Dv, (unsigned short*)nullptr, out, bo);
}